// Round 6
// baseline (357.163 us; speedup 1.0000x reference)
//
#include <hip/hip_runtime.h>

// BoxFilter (r=4): 9x9 clamped-window box SUM. Wave-streaming, float4/lane.
// Each wave: 62 active lanes x 4 cols = 248 input cols -> 240 output cols
// (1920 = 8 strips x 240). Streams SH=27 output rows per segment (40 segs).
// Horizontal 9-sum: per-lane prefix/suffix + 5 shuffles per 4 outputs.
//
// R6 == R5 resubmitted verbatim: R5's bench died on container acquisition
// (infra), the kernel never ran. Theory unchanged:
// R5 restructure: NO register ring, NO staged prefetch. Vertical sliding
// window keeps only the running sum vs; the DEPARTING row (read 9 iters ago,
// guaranteed L2/LLC-warm) is RE-LOADED instead of held in registers.
// Rationale: R1-R4 proved hipcc's pressure-aware scheduler collapses every
// cross-iteration software pipeline back to depth-1 (VGPR_Count pinned at 48
// through batch staging, loop-carried prefetch, sched_barrier(0), and asm
// memory clobber). So make deep MLP the dataflow-NATURAL schedule instead:
// two output rows per iteration need 4 independent loads consumed at the same
// program point -> compiler's canonical codegen batch-issues all 4 with one
// progressive waitcnt. Depth-4 per wave vs depth-1 before (Little's law:
// 2.6 TB/s == 3.8 KB/CU in flight; need ~9 KB/CU for ~6 TB/s).
// Also deletes 72 VGPRs of ring/staging pressure.
// Hard-coded B=8,C=3,H=1080,W=1920,r=4.

#define W_IMG 1920
#define H_IMG 1080
#define SH 27          // output rows per segment (1080 = 40*27)
#define R 4

typedef float f4 __attribute__((ext_vector_type(4)));

#define HOUT()                                                            \
    {                                                                     \
        const float s3 = vs.w;                 /* suffixes */             \
        const float s2 = vs.z + s3;                                       \
        const float s1 = vs.y + s2;                                       \
        const float S  = vs.x + s1;            /* full 4-sum */           \
        const float p2 = vs.x + vs.y;          /* prefixes */             \
        const float p3 = p2 + vs.z;                                       \
        const float T  = __shfl_down(S, 1);    /* fullsum of lane+1 */    \
        const float q1 = __shfl_down(vs.x, 2); /* prefixes of lane+2 */   \
        const float q2 = __shfl_down(p2, 2);                              \
        const float q3 = __shfl_down(p3, 2);                              \
        const float q4 = __shfl_down(S, 2);                               \
        f4 h;                                                             \
        h.x = S  + T + q1;                                                \
        h.y = s1 + T + q2;                                                \
        h.z = s2 + T + q3;                                                \
        h.w = s3 + T + q4;                                                \
        if (stOK) __builtin_nontemporal_store(h, (f4*)po);                \
        po += W_IMG;                                                      \
    }

__global__ void __launch_bounds__(256, 8)
box9_wave4(const float* __restrict__ x, float* __restrict__ out) {
    const int lane  = threadIdx.x & 63;
    const int wv    = threadIdx.x >> 6;
    const int strip = blockIdx.x * 4 + wv;     // 0..7
    const int seg   = blockIdx.y;              // 0..39
    const int img   = blockIdx.z;              // 0..23
    const long base = (long)img * (H_IMG * W_IMG);

    // Lane l covers input cols cin_raw..cin_raw+3 (lane 0 = left halo).
    const int  cin_raw = strip * 240 - 4 + 4 * lane;
    const int  cin     = min(max(cin_raw, 0), W_IMG - 4);  // clamped (valid addr)
    const bool colOK   = (cin_raw >= 0) && (cin_raw + 3 < W_IMG);
    const int  cout    = strip * 240 + 4 * lane;
    const bool stOK    = (lane < 60);

    const int row0 = seg * SH;
    const float* pcol = x + base + cin;        // + row*W_IMG added per row
    float* po = out + base + (long)row0 * W_IMG + cout;

    f4 vs = {0.f, 0.f, 0.f, 0.f};
    const f4 zero = {0.f, 0.f, 0.f, 0.f};

    // Init window for output row row0: input rows row0-4 .. row0+4.
    // 9 independent loads, batched naturally (consumed at one point).
    {
        f4 w[9];
#pragma unroll
        for (int t = 0; t < 9; ++t) {
            const int row = row0 - R + t;
            const int rc  = min(max(row, 0), H_IMG - 1);
            w[t] = *(const f4*)(pcol + (long)rc * W_IMG);
        }
#pragma unroll
        for (int t = 0; t < 9; ++t) {
            const int row = row0 - R + t;     // row0+4 <= 1057 < H: no upper check
            f4 v = w[t];
            if (row < 0 || !colOK) v = zero;
            vs += v;
        }
        HOUT();                               // output row row0
    }

    // Main: 13 pairs of output rows; 4 INDEPENDENT loads per pair body
    // (2 incoming, 2 departing re-loads -- departing rows are L2/LLC-warm).
#pragma unroll 2
    for (int j = 1; j < SH; j += 2) {
        const int r    = row0 + j;
        const int rin0 = r + R;               // incoming for output r
        const int rin1 = r + R + 1;           // incoming for output r+1
        const int rd0  = r - R - 1;           // departing for output r
        const int rd1  = r - R;               // departing for output r+1

        f4 a = *(const f4*)(pcol + (long)min(rin0, H_IMG - 1) * W_IMG);
        f4 b = *(const f4*)(pcol + (long)max(rd0, 0) * W_IMG);
        f4 c = *(const f4*)(pcol + (long)min(rin1, H_IMG - 1) * W_IMG);
        f4 d = *(const f4*)(pcol + (long)max(rd1, 0) * W_IMG);

        if (rin0 >= H_IMG || !colOK) a = zero;
        if (rd0 < 0      || !colOK) b = zero;
        vs += a;
        vs -= b;
        HOUT();                               // output row r

        if (rin1 >= H_IMG || !colOK) c = zero;
        if (rd1 < 0      || !colOK) d = zero;
        vs += c;
        vs -= d;
        HOUT();                               // output row r+1
    }
}

extern "C" void kernel_launch(void* const* d_in, const int* in_sizes, int n_in,
                              void* d_out, int out_size, void* d_ws, size_t ws_size,
                              hipStream_t stream) {
    const float* x = (const float*)d_in[0];
    float* out = (float*)d_out;
    // 8 strips (2 blocks x 4 waves), 40 row segments, 24 images
    dim3 grid(2, 40, 24);
    box9_wave4<<<grid, 256, 0, stream>>>(x, out);
}